// Round 11
// baseline (98.294 us; speedup 1.0000x reference)
//
#include <hip/hip_runtime.h>

// B=16, N=2048, C=128, S=25, D_AGG=128, D_OUT=128
// in: A[16,2048,2048] f32, X[16,2048,128] f32, Wa[128,128] f32, ba[128] f32,
//     Wc[256,128] f32, bc[128] f32, n_samples i32
// out: [16,2048,128] f32
//
// Pipeline (R4 structure; K2 scan staged via global_load_lds for MLP):
//   prep   : Wa -> Wat bf16^T (64 blocks)
//   K1     : H = relu(X @ Wa + ba) -> bf16 [32768][128] (MFMA)
//   K2     : per wave: 8x global_load_lds (whole 8KB A row in flight, no
//            VGPR cost) -> vmcnt(0) -> ballot-rank scan from LDS (mbcnt) ->
//            batched 32-wide gather-max. Batch-affine XCD mapping.
//            Blocks >= 8192: Wct prep.
//   K3     : out = relu([X|agg] @ Wc + bc) -> f32 + partial sumsq (MFMA)
//   K5     : out *= 1/frobnorm per batch (div_no_nan)
//
// ws: H 8MB @0, agg 8MB @8M, Wat 32K @16M, Wct 64K @16M+32K, partials @16M+128K

typedef __attribute__((ext_vector_type(8))) short short8;   // bf16x8 raw bits
typedef __attribute__((ext_vector_type(4))) float f32x4;
typedef __attribute__((ext_vector_type(4))) float fvec4;
typedef unsigned int uint;
typedef unsigned short ushort;

__device__ __forceinline__ ushort f2bf(float x) {           // RNE f32->bf16
    uint u = __builtin_bit_cast(uint, x);
    u += 0x7FFFu + ((u >> 16) & 1u);
    return (ushort)(u >> 16);
}
__device__ __forceinline__ float bflo(uint h) { uint v = h << 16;         return __builtin_bit_cast(float, v); }
__device__ __forceinline__ float bfhi(uint h) { uint v = h & 0xFFFF0000u; return __builtin_bit_cast(float, v); }
// popcount(mask & lanemask_lt) in 2 VALU ops
__device__ __forceinline__ int mbcnt64(unsigned long long m) {
    return __builtin_amdgcn_mbcnt_hi((uint)(m >> 32),
           __builtin_amdgcn_mbcnt_lo((uint)m, 0u));
}

// ---------------------------------------------------------------------------
// prep: Wat[d*128+k] = bf16(Wa[k][d])  (16384 elems, 64 blocks)
// ---------------------------------------------------------------------------
__global__ __launch_bounds__(256) void prep_w_k(
    const float* __restrict__ Wa, ushort* __restrict__ Wat)
{
    int i = blockIdx.x * 256 + threadIdx.x;     // < 16384
    int d = i >> 7, k = i & 127;
    Wat[i] = f2bf(Wa[k * 128 + d]);
}

// ---------------------------------------------------------------------------
// MFMA GEMM (R4-proven): 128x128 tile, 4 waves 2x2, wave = 64x64 = 4x4 frags
// of 16x16x32. Chunk0 converted from fp32, chunk1 (K3) bf16. B pre-transposed
// [col][k]. LDS XOR swizzle on 16B granules (write AND read).
// ---------------------------------------------------------------------------
__global__ __launch_bounds__(256) void gemm_mfma_k(
    const float*  __restrict__ Xf,       // fp32 A source, chunk 0
    const ushort* __restrict__ A1,       // bf16 A source, chunk 1 (or null)
    const ushort* __restrict__ Bt,       // [128][KT] bf16
    const float*  __restrict__ bias,     // [128]
    ushort* __restrict__ outH,           // bf16 out (K1) or null
    float*  __restrict__ outF,           // f32 out (K3) or null
    float*  __restrict__ partials,       // [gridDim.x] sumsq or null
    int ktiles)
{
    __shared__ ushort Asm[128 * 128];
    __shared__ ushort Bsm[128 * 128];
    __shared__ float wred[4];
    const int tid = threadIdx.x;
    const int l = tid & 63, w = tid >> 6;
    const int wm = (w >> 1) * 64, wn = (w & 1) * 64;
    const size_t row0 = (size_t)blockIdx.x * 128;
    const int KT = ktiles << 7;

    f32x4 acc[4][4] = {};

    for (int t = 0; t < ktiles; ++t) {
        __syncthreads();
        if (t == 0) {
#pragma unroll
            for (int j = 0; j < 8; ++j) {
                int gid = (j << 8) + tid;          // 16B granule id
                int r = gid >> 4, g = gid & 15;
                const float* s = Xf + (row0 + r) * 128 + g * 8;
                short8 pk;
#pragma unroll
                for (int e = 0; e < 8; ++e) pk[e] = (short)f2bf(s[e]);
                *(short8*)&Asm[r * 128 + ((g ^ (r & 7)) << 3)] = pk;
            }
        } else {
#pragma unroll
            for (int j = 0; j < 8; ++j) {
                int gid = (j << 8) + tid;
                int r = gid >> 4, g = gid & 15;
                short8 v = *(const short8*)(A1 + (row0 + r) * 128 + g * 8);
                *(short8*)&Asm[r * 128 + ((g ^ (r & 7)) << 3)] = v;
            }
        }
#pragma unroll
        for (int j = 0; j < 8; ++j) {
            int gid = (j << 8) + tid;
            int r = gid >> 4, g = gid & 15;
            short8 v = *(const short8*)(Bt + (size_t)r * KT + (t << 7) + g * 8);
            *(short8*)&Bsm[r * 128 + ((g ^ (r & 7)) << 3)] = v;
        }
        __syncthreads();
#pragma unroll
        for (int ks = 0; ks < 4; ++ks) {
            int gg = (ks << 2) + (l >> 4);
            short8 af[4], bfr[4];
#pragma unroll
            for (int m = 0; m < 4; ++m) {
                int r = wm + m * 16 + (l & 15);
                af[m] = *(const short8*)&Asm[r * 128 + ((gg ^ (r & 7)) << 3)];
            }
#pragma unroll
            for (int n = 0; n < 4; ++n) {
                int c = wn + n * 16 + (l & 15);
                bfr[n] = *(const short8*)&Bsm[c * 128 + ((gg ^ (c & 7)) << 3)];
            }
#pragma unroll
            for (int m = 0; m < 4; ++m)
#pragma unroll
                for (int n = 0; n < 4; ++n)
                    acc[m][n] = __builtin_amdgcn_mfma_f32_16x16x32_bf16(
                        af[m], bfr[n], acc[m][n], 0, 0, 0);
        }
    }

    float bcol[4];
#pragma unroll
    for (int n = 0; n < 4; ++n) bcol[n] = bias[wn + n * 16 + (l & 15)];
    float lsum = 0.f;
#pragma unroll
    for (int m = 0; m < 4; ++m) {
        int rbase = wm + m * 16 + ((l >> 4) << 2);   // C/D: row = 4*(l>>4)+reg
#pragma unroll
        for (int n = 0; n < 4; ++n) {
            int col = wn + n * 16 + (l & 15);        // C/D: col = l&15
#pragma unroll
            for (int r = 0; r < 4; ++r) {
                float v = fmaxf(acc[m][n][r] + bcol[n], 0.f);
                size_t o = (row0 + rbase + r) * 128 + col;
                if (outH) outH[o] = f2bf(v);
                else { outF[o] = v; lsum += v * v; }
            }
        }
    }
    if (partials) {
#pragma unroll
        for (int off = 32; off > 0; off >>= 1) lsum += __shfl_down(lsum, off);
        if (l == 0) wred[w] = lsum;
        __syncthreads();
        if (tid == 0) partials[blockIdx.x] = wred[0] + wred[1] + wred[2] + wred[3];
    }
}

// ---------------------------------------------------------------------------
// K2: one wave per node. A-row staged via global_load_lds: 8 x (64 lanes x
// 16B) = whole 8KB row in flight per wave with no VGPR landing registers ->
// in-flight bytes per CU no longer VGPR-capped (R7/R10 lesson: scan was
// MLP-limited). After vmcnt(0), ballot-rank scan reads the row from LDS
// (identical math to R4; mbcnt for rank popcounts). Then R4's batched
// 32-wide gather-max (batch-affine XCD mapping keeps H slice in local L2).
// Blocks >= 8192: Wct[d*256+k] = bf16(Wc[k][d]) prep for K3.
// ---------------------------------------------------------------------------
__global__ __launch_bounds__(256) void agg_k(
    const float* __restrict__ A,        // [32768][2048]
    const uint*  __restrict__ Hu,       // [32768][64] (bf16 pairs)
    const float* __restrict__ ba,
    uint* __restrict__ aggu,            // [32768][64] (bf16 pairs)
    const int* __restrict__ nsp,
    const float* __restrict__ Wc,       // for folded prep
    ushort* __restrict__ Wct)
{
    if (blockIdx.x >= 8192) {           // folded Wct prep: 128 blocks
        int j = (blockIdx.x - 8192) * 256 + threadIdx.x;   // < 32768
        int d = j >> 8, k = j & 255;
        Wct[j] = f2bf(Wc[k * 128 + d]);
        return;
    }

    __shared__ float Arow[4][2048];     // 8 KB per wave
    __shared__ int idxs[4][32];
    const int l = threadIdx.x & 63;
    const int w = threadIdx.x >> 6;
    const int bid   = blockIdx.x;
    const int xcd   = bid & 7;
    const int grp   = bid >> 3;                  // 0..1023
    const int batch = ((grp >> 9) << 3) + xcd;   // {xcd, xcd+8}
    const int node  = (batch << 11) + ((grp & 511) << 2) + w;
    int S = nsp[0]; if (S > 32) S = 32;

    // async stage: whole row -> LDS, 8 KB in flight, ~0 VGPR cost
    {
        const char* rowb = (const char*)(A + (size_t)node * 2048);
#pragma unroll
        for (int c = 0; c < 8; ++c)
            __builtin_amdgcn_global_load_lds(
                (const __attribute__((address_space(1))) void*)
                    (rowb + c * 1024 + l * 16),
                (__attribute__((address_space(3))) void*)&Arow[w][c * 256],
                16, 0, 0);
    }
    asm volatile("s_waitcnt vmcnt(0)" ::: "memory");
    __builtin_amdgcn_sched_barrier(0);

    // rank-based ballot scan from LDS (same math as R4, mbcnt ranks)
    int base = 0;
#pragma unroll
    for (int c = 0; c < 8; ++c) {
        if (base < S) {                              // wave-uniform skip
            fvec4 v = *(const fvec4*)&Arow[w][c * 256 + l * 4];
            unsigned long long m0 = __ballot(v[0] != 0.f);
            unsigned long long m1 = __ballot(v[1] != 0.f);
            unsigned long long m2 = __ballot(v[2] != 0.f);
            unsigned long long m3 = __ballot(v[3] != 0.f);
            int below = mbcnt64(m0) + mbcnt64(m1) + mbcnt64(m2) + mbcnt64(m3);
            int o0 = (int)((m0 >> l) & 1), o1 = (int)((m1 >> l) & 1);
            int o2 = (int)((m2 >> l) & 1), o3 = (int)((m3 >> l) & 1);
            int r0 = base + below;
            int r1 = r0 + o0, r2 = r1 + o1, r3 = r2 + o2;
            int e = (c << 8) + (l << 2);
            if (o0 && r0 < S) idxs[w][r0] = e;
            if (o1 && r1 < S) idxs[w][r1] = e + 1;
            if (o2 && r2 < S) idxs[w][r2] = e + 2;
            if (o3 && r3 < S) idxs[w][r3] = e + 3;
            base += __popcll(m0) + __popcll(m1) + __popcll(m2) + __popcll(m3);
        }
    }
    int found = base < S ? base : S;

    float i0 = fmaxf(ba[2 * l], 0.f), i1 = fmaxf(ba[2 * l + 1], 0.f);
    float r0f = i0, r1f = i1;
    if (found > 0) {
        int fill = idxs[w][0];                       // broadcast read
        if (l < 32)                                  // pad list to 32
            idxs[w][l] = (l < found) ? idxs[w][l] : fill;

        const uint* HB = Hu + ((size_t)batch << 17); // batch*2048*64
        uint h[32];
#pragma unroll
        for (int q = 0; q < 32; ++q)                 // all 32 in flight
            h[q] = HB[(size_t)idxs[w][q] * 64 + l];

        float a0[8], a1[8];
#pragma unroll
        for (int q = 0; q < 8; ++q) { a0[q] = i0; a1[q] = i1; }
#pragma unroll
        for (int q = 0; q < 32; ++q) {
            a0[q & 7] = fmaxf(a0[q & 7], bflo(h[q]));
            a1[q & 7] = fmaxf(a1[q & 7], bfhi(h[q]));
        }
#pragma unroll
        for (int q = 0; q < 4; ++q) {
            a0[q] = fmaxf(a0[q], a0[q + 4]);
            a1[q] = fmaxf(a1[q], a1[q + 4]);
        }
        r0f = fmaxf(fmaxf(a0[0], a0[1]), fmaxf(a0[2], a0[3]));
        r1f = fmaxf(fmaxf(a1[0], a1[1]), fmaxf(a1[2], a1[3]));
    }
    aggu[(size_t)node * 64 + l] = (uint)f2bf(r0f) | ((uint)f2bf(r1f) << 16);
}

// ---------------------------------------------------------------------------
// K5: per-batch frobenius normalize in place; each block deterministically
// reduces its batch's 16 partials. div_no_nan: norm==0 -> 0.
// ---------------------------------------------------------------------------
__global__ __launch_bounds__(256) void scale_k(
    float* __restrict__ out, const float* __restrict__ partials)
{
    const int blk = blockIdx.x;
    const int b = blk >> 6;                          // 64 blocks per batch
    float s = 0.f;
#pragma unroll
    for (int i = 0; i < 16; ++i) s += partials[b * 16 + i];
    float norm = sqrtf(s);
    float sc = (norm > 0.f) ? (1.f / norm) : 0.f;
    fvec4* o4 = (fvec4*)out;
    int i0 = blk * 1024 + threadIdx.x;
#pragma unroll
    for (int k = 0; k < 4; ++k) {
        fvec4 v = o4[i0 + k * 256];
        o4[i0 + k * 256] = v * sc;
    }
}

extern "C" void kernel_launch(void* const* d_in, const int* in_sizes, int n_in,
                              void* d_out, int out_size, void* d_ws, size_t ws_size,
                              hipStream_t stream) {
    const float* A  = (const float*)d_in[0];
    const float* X  = (const float*)d_in[1];
    const float* Wa = (const float*)d_in[2];
    const float* ba = (const float*)d_in[3];
    const float* Wc = (const float*)d_in[4];
    const float* bc = (const float*)d_in[5];
    const int*  nsp = (const int*)d_in[6];

    float* out = (float*)d_out;
    char* ws = (char*)d_ws;
    ushort* H        = (ushort*)ws;                              // 8 MB
    ushort* agg      = (ushort*)(ws + (8u << 20));               // 8 MB
    ushort* Wat      = (ushort*)(ws + (16u << 20));              // 32 KB
    ushort* Wct      = (ushort*)(ws + (16u << 20) + 32768);      // 64 KB
    float*  partials = (float*) (ws + (16u << 20) + 131072);     // 1 KB

    // Wa -> bf16 transposed
    prep_w_k<<<64, 256, 0, stream>>>(Wa, Wat);
    // K1: H = relu(X @ Wa + ba), bf16
    gemm_mfma_k<<<256, 256, 0, stream>>>(X, nullptr, Wat, ba, H, nullptr, nullptr, 1);
    // K2: gll-staged scan + batched gather (+ folded Wct prep blocks >= 8192)
    agg_k<<<8192 + 128, 256, 0, stream>>>(A, (const uint*)H, ba, (uint*)agg,
                                          nsp, Wc, Wct);
    // K3: out = relu([X|agg] @ Wc + bc) + partial sumsq
    gemm_mfma_k<<<256, 256, 0, stream>>>(X, agg, Wct, bc, nullptr, out, partials, 2);
    // K5: normalize
    scale_k<<<1024, 256, 0, stream>>>(out, partials);
}

// Round 12
// 81.893 us; speedup vs baseline: 1.2003x; 1.2003x over previous
//
#include <hip/hip_runtime.h>

// B=16, N=2048, C=128, S=25, D_AGG=128, D_OUT=128
// in: A[16,2048,2048] f32, X[16,2048,128] f32, Wa[128,128] f32, ba[128] f32,
//     Wc[256,128] f32, bc[128] f32, n_samples i32
// out: [16,2048,128] f32
//
// Pipeline (R4 structure, prep dispatch removed, mbcnt scan):
//   K1     : H = relu(X @ Wa + ba) -> bf16 [32768][128] (MFMA; Wa transposed
//            +converted inline during B-staging — no prep kernel)
//   K2     : agg = max over first-S neighbors of H rows (rank-scan + 32-wide
//            batched gather; batch-affine XCD mapping for H L2 locality)
//            + blocks >= 8192 prep Wc -> Wct bf16
//   K3     : out = relu([X|agg] @ Wc + bc) -> f32 + partial sumsq (MFMA)
//   K5     : out *= 1/frobnorm per batch (div_no_nan)
//
// ws: H 8MB @0, agg 8MB @8M, Wct 64K @16M, partials 1K @16M+64K

typedef __attribute__((ext_vector_type(8))) short short8;   // bf16x8 raw bits
typedef __attribute__((ext_vector_type(4))) float f32x4;
typedef __attribute__((ext_vector_type(4))) float fvec4;
typedef unsigned int uint;
typedef unsigned short ushort;

__device__ __forceinline__ ushort f2bf(float x) {           // RNE f32->bf16
    uint u = __builtin_bit_cast(uint, x);
    u += 0x7FFFu + ((u >> 16) & 1u);
    return (ushort)(u >> 16);
}
__device__ __forceinline__ float bflo(uint h) { uint v = h << 16;         return __builtin_bit_cast(float, v); }
__device__ __forceinline__ float bfhi(uint h) { uint v = h & 0xFFFF0000u; return __builtin_bit_cast(float, v); }
// popcount(mask & lanemask_lt) in 2 VALU ops (R9/R11-proven)
__device__ __forceinline__ int mbcnt64(unsigned long long m) {
    return __builtin_amdgcn_mbcnt_hi((uint)(m >> 32),
           __builtin_amdgcn_mbcnt_lo((uint)m, 0u));
}

// ---------------------------------------------------------------------------
// K1: H = relu(X @ Wa + ba) -> bf16. 128x128 tile, 4 waves 2x2, wave = 64x64
// = 4x4 frags of 16x16x32. A staged from fp32 X (convert); B staged by
// inline transpose+convert of Wa (64 KB, L2-broadcast across blocks) —
// R9-proven. LDS XOR swizzle on 16B granules (write AND read).
// ---------------------------------------------------------------------------
__global__ __launch_bounds__(256) void gemm_k1_k(
    const float* __restrict__ X, const float* __restrict__ Wa,
    const float* __restrict__ ba, ushort* __restrict__ H)
{
    __shared__ ushort Asm[128 * 128];
    __shared__ ushort Bsm[128 * 128];
    const int tid = threadIdx.x, l = tid & 63, w = tid >> 6;
    const int wm = (w >> 1) * 64, wn = (w & 1) * 64;
    const size_t row0 = (size_t)blockIdx.x * 128;

    // stage A: X f32 -> bf16, swizzled
#pragma unroll
    for (int j = 0; j < 8; ++j) {
        int gid = (j << 8) + tid;              // 16B granule id
        int r = gid >> 4, g = gid & 15;
        const float* s = X + (row0 + r) * 128 + g * 8;
        short8 pk;
#pragma unroll
        for (int e = 0; e < 8; ++e) pk[e] = (short)f2bf(s[e]);
        *(short8*)&Asm[r * 128 + ((g ^ (r & 7)) << 3)] = pk;
    }
    // stage B: Wa[k][d] f32 -> Bsm[d][k] bf16 (inline transpose+convert)
    {
        int c = tid >> 1;                      // output col d
        int g0 = (tid & 1) * 8;                // granule half
#pragma unroll
        for (int g = g0; g < g0 + 8; ++g) {
            short8 pk;
#pragma unroll
            for (int e = 0; e < 8; ++e)
                pk[e] = (short)f2bf(Wa[(size_t)(g * 8 + e) * 128 + c]);
            *(short8*)&Bsm[c * 128 + ((g ^ (c & 7)) << 3)] = pk;
        }
    }
    __syncthreads();

    f32x4 acc[4][4] = {};
#pragma unroll
    for (int ks = 0; ks < 4; ++ks) {
        int gg = (ks << 2) + (l >> 4);
        short8 af[4], bfr[4];
#pragma unroll
        for (int m = 0; m < 4; ++m) {
            int r = wm + m * 16 + (l & 15);
            af[m] = *(const short8*)&Asm[r * 128 + ((gg ^ (r & 7)) << 3)];
        }
#pragma unroll
        for (int n = 0; n < 4; ++n) {
            int c = wn + n * 16 + (l & 15);
            bfr[n] = *(const short8*)&Bsm[c * 128 + ((gg ^ (c & 7)) << 3)];
        }
#pragma unroll
        for (int m = 0; m < 4; ++m)
#pragma unroll
            for (int n = 0; n < 4; ++n)
                acc[m][n] = __builtin_amdgcn_mfma_f32_16x16x32_bf16(
                    af[m], bfr[n], acc[m][n], 0, 0, 0);
    }

    float bcol[4];
#pragma unroll
    for (int n = 0; n < 4; ++n) bcol[n] = ba[wn + n * 16 + (l & 15)];
#pragma unroll
    for (int m = 0; m < 4; ++m) {
        int rbase = wm + m * 16 + ((l >> 4) << 2);   // C/D: row = 4*(l>>4)+reg
#pragma unroll
        for (int n = 0; n < 4; ++n) {
            int col = wn + n * 16 + (l & 15);        // C/D: col = l&15
#pragma unroll
            for (int r = 0; r < 4; ++r)
                H[(row0 + rbase + r) * 128 + col] =
                    f2bf(fmaxf(acc[m][n][r] + bcol[n], 0.f));
        }
    }
}

// ---------------------------------------------------------------------------
// K2 (R4-proven, mbcnt ranks): one wave per node. Batch-affine XCD mapping
// (batch = {xcd, xcd+8}) keeps each batch's 512 KB H slice in one L2.
// Rank-based ballot scan -> first min(deg,S) ascending indices (== lax.top_k
// of binary mask) -> LDS; pad to 32 with idxs[0] (max idempotent); 32
// gathers all in flight. acc init = relu(ba) (= padded slot value).
// A loads nontemporal. Blocks >= 8192: Wct prep for K3.
// ---------------------------------------------------------------------------
__global__ __launch_bounds__(256) void agg_k(
    const float* __restrict__ A,        // [32768][2048]
    const uint*  __restrict__ Hu,       // [32768][64] (bf16 pairs)
    const float* __restrict__ ba,
    uint* __restrict__ aggu,            // [32768][64] (bf16 pairs)
    const int* __restrict__ nsp,
    const float* __restrict__ Wc,       // for folded prep
    ushort* __restrict__ Wct)
{
    if (blockIdx.x >= 8192) {           // folded Wct prep: 128 blocks
        int j = (blockIdx.x - 8192) * 256 + threadIdx.x;   // < 32768
        int d = j >> 8, k = j & 255;
        Wct[j] = f2bf(Wc[k * 128 + d]);
        return;
    }

    __shared__ int idxs[4][32];
    const int l = threadIdx.x & 63;
    const int w = threadIdx.x >> 6;
    const int bid   = blockIdx.x;
    const int xcd   = bid & 7;
    const int grp   = bid >> 3;                  // 0..1023
    const int batch = ((grp >> 9) << 3) + xcd;   // {xcd, xcd+8}
    const int node  = (batch << 11) + ((grp & 511) << 2) + w;
    int S = nsp[0]; if (S > 32) S = 32;

    const fvec4* rowp = (const fvec4*)(A + (size_t)node * 2048);
    fvec4 v[8];
#pragma unroll
    for (int c = 0; c < 8; ++c)
        v[c] = __builtin_nontemporal_load(rowp + c * 64 + l);

    int base = 0;
#pragma unroll
    for (int c = 0; c < 8; ++c) {
        if (base < S) {                              // wave-uniform skip
            unsigned long long m0 = __ballot(v[c][0] != 0.f);
            unsigned long long m1 = __ballot(v[c][1] != 0.f);
            unsigned long long m2 = __ballot(v[c][2] != 0.f);
            unsigned long long m3 = __ballot(v[c][3] != 0.f);
            int below = mbcnt64(m0) + mbcnt64(m1) + mbcnt64(m2) + mbcnt64(m3);
            int o0 = (int)((m0 >> l) & 1), o1 = (int)((m1 >> l) & 1);
            int o2 = (int)((m2 >> l) & 1), o3 = (int)((m3 >> l) & 1);
            int r0 = base + below;
            int r1 = r0 + o0, r2 = r1 + o1, r3 = r2 + o2;
            int e = (c << 8) + (l << 2);
            if (o0 && r0 < S) idxs[w][r0] = e;
            if (o1 && r1 < S) idxs[w][r1] = e + 1;
            if (o2 && r2 < S) idxs[w][r2] = e + 2;
            if (o3 && r3 < S) idxs[w][r3] = e + 3;
            base += __popcll(m0) + __popcll(m1) + __popcll(m2) + __popcll(m3);
        }
    }
    int found = base < S ? base : S;

    float i0 = fmaxf(ba[2 * l], 0.f), i1 = fmaxf(ba[2 * l + 1], 0.f);
    float r0f = i0, r1f = i1;
    if (found > 0) {
        int fill = idxs[w][0];                       // broadcast read
        if (l < 32)                                  // pad list to 32
            idxs[w][l] = (l < found) ? idxs[w][l] : fill;

        const uint* HB = Hu + ((size_t)batch << 17); // batch*2048*64
        uint h[32];
#pragma unroll
        for (int q = 0; q < 32; ++q)                 // all 32 in flight
            h[q] = HB[(size_t)idxs[w][q] * 64 + l];

        float a0[8], a1[8];
#pragma unroll
        for (int q = 0; q < 8; ++q) { a0[q] = i0; a1[q] = i1; }
#pragma unroll
        for (int q = 0; q < 32; ++q) {
            a0[q & 7] = fmaxf(a0[q & 7], bflo(h[q]));
            a1[q & 7] = fmaxf(a1[q & 7], bfhi(h[q]));
        }
#pragma unroll
        for (int q = 0; q < 4; ++q) {
            a0[q] = fmaxf(a0[q], a0[q + 4]);
            a1[q] = fmaxf(a1[q], a1[q + 4]);
        }
        r0f = fmaxf(fmaxf(a0[0], a0[1]), fmaxf(a0[2], a0[3]));
        r1f = fmaxf(fmaxf(a1[0], a1[1]), fmaxf(a1[2], a1[3]));
    }
    aggu[(size_t)node * 64 + l] = (uint)f2bf(r0f) | ((uint)f2bf(r1f) << 16);
}

// ---------------------------------------------------------------------------
// K3 (R4-proven): out = relu([X|agg] @ Wc + bc) + per-block sumsq partials.
// ---------------------------------------------------------------------------
__global__ __launch_bounds__(256) void gemm_k3_k(
    const float* __restrict__ X, const ushort* __restrict__ agg,
    const ushort* __restrict__ Wct, const float* __restrict__ bc,
    float* __restrict__ out, float* __restrict__ partials)
{
    __shared__ ushort Asm[128 * 128];
    __shared__ ushort Bsm[128 * 128];
    __shared__ float wred[4];
    const int tid = threadIdx.x, l = tid & 63, w = tid >> 6;
    const int wm = (w >> 1) * 64, wn = (w & 1) * 64;
    const size_t row0 = (size_t)blockIdx.x * 128;

    f32x4 acc[4][4] = {};
    for (int t = 0; t < 2; ++t) {
        __syncthreads();
        if (t == 0) {
#pragma unroll
            for (int j = 0; j < 8; ++j) {
                int gid = (j << 8) + tid;
                int r = gid >> 4, g = gid & 15;
                const float* s = X + (row0 + r) * 128 + g * 8;
                short8 pk;
#pragma unroll
                for (int e = 0; e < 8; ++e) pk[e] = (short)f2bf(s[e]);
                *(short8*)&Asm[r * 128 + ((g ^ (r & 7)) << 3)] = pk;
            }
        } else {
#pragma unroll
            for (int j = 0; j < 8; ++j) {
                int gid = (j << 8) + tid;
                int r = gid >> 4, g = gid & 15;
                short8 v = *(const short8*)(agg + (row0 + r) * 128 + g * 8);
                *(short8*)&Asm[r * 128 + ((g ^ (r & 7)) << 3)] = v;
            }
        }
#pragma unroll
        for (int j = 0; j < 8; ++j) {
            int gid = (j << 8) + tid;
            int r = gid >> 4, g = gid & 15;
            short8 v = *(const short8*)(Wct + (size_t)r * 256 + (t << 7) + g * 8);
            *(short8*)&Bsm[r * 128 + ((g ^ (r & 7)) << 3)] = v;
        }
        __syncthreads();
#pragma unroll
        for (int ks = 0; ks < 4; ++ks) {
            int gg = (ks << 2) + (l >> 4);
            short8 af[4], bfr[4];
#pragma unroll
            for (int m = 0; m < 4; ++m) {
                int r = wm + m * 16 + (l & 15);
                af[m] = *(const short8*)&Asm[r * 128 + ((gg ^ (r & 7)) << 3)];
            }
#pragma unroll
            for (int n = 0; n < 4; ++n) {
                int c = wn + n * 16 + (l & 15);
                bfr[n] = *(const short8*)&Bsm[c * 128 + ((gg ^ (c & 7)) << 3)];
            }
#pragma unroll
            for (int m = 0; m < 4; ++m)
#pragma unroll
                for (int n = 0; n < 4; ++n)
                    acc[m][n] = __builtin_amdgcn_mfma_f32_16x16x32_bf16(
                        af[m], bfr[n], acc[m][n], 0, 0, 0);
        }
    }

    float bcol[4];
#pragma unroll
    for (int n = 0; n < 4; ++n) bcol[n] = bc[wn + n * 16 + (l & 15)];
    float lsum = 0.f;
#pragma unroll
    for (int m = 0; m < 4; ++m) {
        int rbase = wm + m * 16 + ((l >> 4) << 2);   // C/D: row = 4*(l>>4)+reg
#pragma unroll
        for (int n = 0; n < 4; ++n) {
            int col = wn + n * 16 + (l & 15);        // C/D: col = l&15
#pragma unroll
            for (int r = 0; r < 4; ++r) {
                float v = fmaxf(acc[m][n][r] + bcol[n], 0.f);
                out[(row0 + rbase + r) * 128 + col] = v;
                lsum += v * v;
            }
        }
    }
#pragma unroll
    for (int off = 32; off > 0; off >>= 1) lsum += __shfl_down(lsum, off);
    if (l == 0) wred[w] = lsum;
    __syncthreads();
    if (tid == 0)
        partials[blockIdx.x] = wred[0] + wred[1] + wred[2] + wred[3];
}

// ---------------------------------------------------------------------------
// K5 (R4-proven): per-batch frobenius normalize in place; each block
// deterministically reduces its batch's 16 partials. div_no_nan.
// ---------------------------------------------------------------------------
__global__ __launch_bounds__(256) void scale_k(
    float* __restrict__ out, const float* __restrict__ partials)
{
    const int blk = blockIdx.x;
    const int b = blk >> 6;                          // 64 blocks per batch
    float s = 0.f;
#pragma unroll
    for (int i = 0; i < 16; ++i) s += partials[b * 16 + i];
    float norm = sqrtf(s);
    float sc = (norm > 0.f) ? (1.f / norm) : 0.f;
    fvec4* o4 = (fvec4*)out;
    int i0 = blk * 1024 + threadIdx.x;
#pragma unroll
    for (int k = 0; k < 4; ++k) {
        fvec4 v = o4[i0 + k * 256];
        o4[i0 + k * 256] = v * sc;
    }
}

extern "C" void kernel_launch(void* const* d_in, const int* in_sizes, int n_in,
                              void* d_out, int out_size, void* d_ws, size_t ws_size,
                              hipStream_t stream) {
    const float* A  = (const float*)d_in[0];
    const float* X  = (const float*)d_in[1];
    const float* Wa = (const float*)d_in[2];
    const float* ba = (const float*)d_in[3];
    const float* Wc = (const float*)d_in[4];
    const float* bc = (const float*)d_in[5];
    const int*  nsp = (const int*)d_in[6];

    float* out = (float*)d_out;
    char* ws = (char*)d_ws;
    ushort* H        = (ushort*)ws;                              // 8 MB
    ushort* agg      = (ushort*)(ws + (8u << 20));               // 8 MB
    ushort* Wct      = (ushort*)(ws + (16u << 20));              // 64 KB
    float*  partials = (float*) (ws + (16u << 20) + 65536);      // 1 KB

    // K1: H = relu(X @ Wa + ba), inline Wa transpose (no prep dispatch)
    gemm_k1_k<<<256, 256, 0, stream>>>(X, Wa, ba, H);
    // K2: agg = max over first-S neighbors (+ folded Wct prep blocks >= 8192)
    agg_k<<<8192 + 128, 256, 0, stream>>>(A, (const uint*)H, ba, (uint*)agg,
                                          nsp, Wc, Wct);
    // K3: out = relu([X|agg] @ Wc + bc) + partial sumsq
    gemm_k3_k<<<256, 256, 0, stream>>>(X, agg, Wct, bc, out, partials);
    // K5: normalize
    scale_k<<<1024, 256, 0, stream>>>(out, partials);
}

// Round 13
// 81.634 us; speedup vs baseline: 1.2041x; 1.0032x over previous
//
#include <hip/hip_runtime.h>

// B=16, N=2048, C=128, S=25, D_AGG=128, D_OUT=128
// in: A[16,2048,2048] f32, X[16,2048,128] f32, Wa[128,128] f32, ba[128] f32,
//     Wc[256,128] f32, bc[128] f32, n_samples i32
// out: [16,2048,128] f32
//
// Pipeline (R4 structure, prep dispatch removed, mbcnt scan):
//   K1     : H = relu(X @ Wa + ba) -> bf16 [32768][128] (MFMA; Wa transposed
//            +converted inline during B-staging — no prep kernel)
//   K2     : agg = max over first-S neighbors of H rows (rank-scan + 32-wide
//            batched gather; batch-affine XCD mapping for H L2 locality)
//            + blocks >= 8192 prep Wc -> Wct bf16
//   K3     : out = relu([X|agg] @ Wc + bc) -> f32 + partial sumsq (MFMA)
//   K5     : out *= 1/frobnorm per batch (div_no_nan)
//
// ws: H 8MB @0, agg 8MB @8M, Wct 64K @16M, partials 1K @16M+64K

typedef __attribute__((ext_vector_type(8))) short short8;   // bf16x8 raw bits
typedef __attribute__((ext_vector_type(4))) float f32x4;
typedef __attribute__((ext_vector_type(4))) float fvec4;
typedef unsigned int uint;
typedef unsigned short ushort;

__device__ __forceinline__ ushort f2bf(float x) {           // RNE f32->bf16
    uint u = __builtin_bit_cast(uint, x);
    u += 0x7FFFu + ((u >> 16) & 1u);
    return (ushort)(u >> 16);
}
__device__ __forceinline__ float bflo(uint h) { uint v = h << 16;         return __builtin_bit_cast(float, v); }
__device__ __forceinline__ float bfhi(uint h) { uint v = h & 0xFFFF0000u; return __builtin_bit_cast(float, v); }
// popcount(mask & lanemask_lt) in 2 VALU ops (R9/R11-proven)
__device__ __forceinline__ int mbcnt64(unsigned long long m) {
    return __builtin_amdgcn_mbcnt_hi((uint)(m >> 32),
           __builtin_amdgcn_mbcnt_lo((uint)m, 0u));
}

// ---------------------------------------------------------------------------
// K1: H = relu(X @ Wa + ba) -> bf16. 128x128 tile, 4 waves 2x2, wave = 64x64
// = 4x4 frags of 16x16x32. A staged from fp32 X (convert); B staged by
// inline transpose+convert of Wa (64 KB, L2-broadcast across blocks) —
// R9-proven. LDS XOR swizzle on 16B granules (write AND read).
// ---------------------------------------------------------------------------
__global__ __launch_bounds__(256) void gemm_k1_k(
    const float* __restrict__ X, const float* __restrict__ Wa,
    const float* __restrict__ ba, ushort* __restrict__ H)
{
    __shared__ ushort Asm[128 * 128];
    __shared__ ushort Bsm[128 * 128];
    const int tid = threadIdx.x, l = tid & 63, w = tid >> 6;
    const int wm = (w >> 1) * 64, wn = (w & 1) * 64;
    const size_t row0 = (size_t)blockIdx.x * 128;

    // stage A: X f32 -> bf16, swizzled
#pragma unroll
    for (int j = 0; j < 8; ++j) {
        int gid = (j << 8) + tid;              // 16B granule id
        int r = gid >> 4, g = gid & 15;
        const float* s = X + (row0 + r) * 128 + g * 8;
        short8 pk;
#pragma unroll
        for (int e = 0; e < 8; ++e) pk[e] = (short)f2bf(s[e]);
        *(short8*)&Asm[r * 128 + ((g ^ (r & 7)) << 3)] = pk;
    }
    // stage B: Wa[k][d] f32 -> Bsm[d][k] bf16 (inline transpose+convert)
    {
        int c = tid >> 1;                      // output col d
        int g0 = (tid & 1) * 8;                // granule half
#pragma unroll
        for (int g = g0; g < g0 + 8; ++g) {
            short8 pk;
#pragma unroll
            for (int e = 0; e < 8; ++e)
                pk[e] = (short)f2bf(Wa[(size_t)(g * 8 + e) * 128 + c]);
            *(short8*)&Bsm[c * 128 + ((g ^ (c & 7)) << 3)] = pk;
        }
    }
    __syncthreads();

    f32x4 acc[4][4] = {};
#pragma unroll
    for (int ks = 0; ks < 4; ++ks) {
        int gg = (ks << 2) + (l >> 4);
        short8 af[4], bfr[4];
#pragma unroll
        for (int m = 0; m < 4; ++m) {
            int r = wm + m * 16 + (l & 15);
            af[m] = *(const short8*)&Asm[r * 128 + ((gg ^ (r & 7)) << 3)];
        }
#pragma unroll
        for (int n = 0; n < 4; ++n) {
            int c = wn + n * 16 + (l & 15);
            bfr[n] = *(const short8*)&Bsm[c * 128 + ((gg ^ (c & 7)) << 3)];
        }
#pragma unroll
        for (int m = 0; m < 4; ++m)
#pragma unroll
            for (int n = 0; n < 4; ++n)
                acc[m][n] = __builtin_amdgcn_mfma_f32_16x16x32_bf16(
                    af[m], bfr[n], acc[m][n], 0, 0, 0);
    }

    float bcol[4];
#pragma unroll
    for (int n = 0; n < 4; ++n) bcol[n] = ba[wn + n * 16 + (l & 15)];
#pragma unroll
    for (int m = 0; m < 4; ++m) {
        int rbase = wm + m * 16 + ((l >> 4) << 2);   // C/D: row = 4*(l>>4)+reg
#pragma unroll
        for (int n = 0; n < 4; ++n) {
            int col = wn + n * 16 + (l & 15);        // C/D: col = l&15
#pragma unroll
            for (int r = 0; r < 4; ++r)
                H[(row0 + rbase + r) * 128 + col] =
                    f2bf(fmaxf(acc[m][n][r] + bcol[n], 0.f));
        }
    }
}

// ---------------------------------------------------------------------------
// K2 (R4-proven, mbcnt ranks): one wave per node. Batch-affine XCD mapping
// (batch = {xcd, xcd+8}) keeps each batch's 512 KB H slice in one L2.
// Rank-based ballot scan -> first min(deg,S) ascending indices (== lax.top_k
// of binary mask) -> LDS; pad to 32 with idxs[0] (max idempotent); 32
// gathers all in flight. acc init = relu(ba) (= padded slot value).
// A loads nontemporal. Blocks >= 8192: Wct prep for K3.
// ---------------------------------------------------------------------------
__global__ __launch_bounds__(256) void agg_k(
    const float* __restrict__ A,        // [32768][2048]
    const uint*  __restrict__ Hu,       // [32768][64] (bf16 pairs)
    const float* __restrict__ ba,
    uint* __restrict__ aggu,            // [32768][64] (bf16 pairs)
    const int* __restrict__ nsp,
    const float* __restrict__ Wc,       // for folded prep
    ushort* __restrict__ Wct)
{
    if (blockIdx.x >= 8192) {           // folded Wct prep: 128 blocks
        int j = (blockIdx.x - 8192) * 256 + threadIdx.x;   // < 32768
        int d = j >> 8, k = j & 255;
        Wct[j] = f2bf(Wc[k * 128 + d]);
        return;
    }

    __shared__ int idxs[4][32];
    const int l = threadIdx.x & 63;
    const int w = threadIdx.x >> 6;
    const int bid   = blockIdx.x;
    const int xcd   = bid & 7;
    const int grp   = bid >> 3;                  // 0..1023
    const int batch = ((grp >> 9) << 3) + xcd;   // {xcd, xcd+8}
    const int node  = (batch << 11) + ((grp & 511) << 2) + w;
    int S = nsp[0]; if (S > 32) S = 32;

    const fvec4* rowp = (const fvec4*)(A + (size_t)node * 2048);
    fvec4 v[8];
#pragma unroll
    for (int c = 0; c < 8; ++c)
        v[c] = __builtin_nontemporal_load(rowp + c * 64 + l);

    int base = 0;
#pragma unroll
    for (int c = 0; c < 8; ++c) {
        if (base < S) {                              // wave-uniform skip
            unsigned long long m0 = __ballot(v[c][0] != 0.f);
            unsigned long long m1 = __ballot(v[c][1] != 0.f);
            unsigned long long m2 = __ballot(v[c][2] != 0.f);
            unsigned long long m3 = __ballot(v[c][3] != 0.f);
            int below = mbcnt64(m0) + mbcnt64(m1) + mbcnt64(m2) + mbcnt64(m3);
            int o0 = (int)((m0 >> l) & 1), o1 = (int)((m1 >> l) & 1);
            int o2 = (int)((m2 >> l) & 1), o3 = (int)((m3 >> l) & 1);
            int r0 = base + below;
            int r1 = r0 + o0, r2 = r1 + o1, r3 = r2 + o2;
            int e = (c << 8) + (l << 2);
            if (o0 && r0 < S) idxs[w][r0] = e;
            if (o1 && r1 < S) idxs[w][r1] = e + 1;
            if (o2 && r2 < S) idxs[w][r2] = e + 2;
            if (o3 && r3 < S) idxs[w][r3] = e + 3;
            base += __popcll(m0) + __popcll(m1) + __popcll(m2) + __popcll(m3);
        }
    }
    int found = base < S ? base : S;

    float i0 = fmaxf(ba[2 * l], 0.f), i1 = fmaxf(ba[2 * l + 1], 0.f);
    float r0f = i0, r1f = i1;
    if (found > 0) {
        int fill = idxs[w][0];                       // broadcast read
        if (l < 32)                                  // pad list to 32
            idxs[w][l] = (l < found) ? idxs[w][l] : fill;

        const uint* HB = Hu + ((size_t)batch << 17); // batch*2048*64
        uint h[32];
#pragma unroll
        for (int q = 0; q < 32; ++q)                 // all 32 in flight
            h[q] = HB[(size_t)idxs[w][q] * 64 + l];

        float a0[8], a1[8];
#pragma unroll
        for (int q = 0; q < 8; ++q) { a0[q] = i0; a1[q] = i1; }
#pragma unroll
        for (int q = 0; q < 32; ++q) {
            a0[q & 7] = fmaxf(a0[q & 7], bflo(h[q]));
            a1[q & 7] = fmaxf(a1[q & 7], bfhi(h[q]));
        }
#pragma unroll
        for (int q = 0; q < 4; ++q) {
            a0[q] = fmaxf(a0[q], a0[q + 4]);
            a1[q] = fmaxf(a1[q], a1[q + 4]);
        }
        r0f = fmaxf(fmaxf(a0[0], a0[1]), fmaxf(a0[2], a0[3]));
        r1f = fmaxf(fmaxf(a1[0], a1[1]), fmaxf(a1[2], a1[3]));
    }
    aggu[(size_t)node * 64 + l] = (uint)f2bf(r0f) | ((uint)f2bf(r1f) << 16);
}

// ---------------------------------------------------------------------------
// K3 (R4-proven): out = relu([X|agg] @ Wc + bc) + per-block sumsq partials.
// ---------------------------------------------------------------------------
__global__ __launch_bounds__(256) void gemm_k3_k(
    const float* __restrict__ X, const ushort* __restrict__ agg,
    const ushort* __restrict__ Wct, const float* __restrict__ bc,
    float* __restrict__ out, float* __restrict__ partials)
{
    __shared__ ushort Asm[128 * 128];
    __shared__ ushort Bsm[128 * 128];
    __shared__ float wred[4];
    const int tid = threadIdx.x, l = tid & 63, w = tid >> 6;
    const int wm = (w >> 1) * 64, wn = (w & 1) * 64;
    const size_t row0 = (size_t)blockIdx.x * 128;

    f32x4 acc[4][4] = {};
    for (int t = 0; t < 2; ++t) {
        __syncthreads();
        if (t == 0) {
#pragma unroll
            for (int j = 0; j < 8; ++j) {
                int gid = (j << 8) + tid;
                int r = gid >> 4, g = gid & 15;
                const float* s = X + (row0 + r) * 128 + g * 8;
                short8 pk;
#pragma unroll
                for (int e = 0; e < 8; ++e) pk[e] = (short)f2bf(s[e]);
                *(short8*)&Asm[r * 128 + ((g ^ (r & 7)) << 3)] = pk;
            }
        } else {
#pragma unroll
            for (int j = 0; j < 8; ++j) {
                int gid = (j << 8) + tid;
                int r = gid >> 4, g = gid & 15;
                short8 v = *(const short8*)(agg + (row0 + r) * 128 + g * 8);
                *(short8*)&Asm[r * 128 + ((g ^ (r & 7)) << 3)] = v;
            }
        }
#pragma unroll
        for (int j = 0; j < 8; ++j) {
            int gid = (j << 8) + tid;
            int r = gid >> 4, g = gid & 15;
            short8 v = *(const short8*)(Wct + (size_t)r * 256 + (t << 7) + g * 8);
            *(short8*)&Bsm[r * 128 + ((g ^ (r & 7)) << 3)] = v;
        }
        __syncthreads();
#pragma unroll
        for (int ks = 0; ks < 4; ++ks) {
            int gg = (ks << 2) + (l >> 4);
            short8 af[4], bfr[4];
#pragma unroll
            for (int m = 0; m < 4; ++m) {
                int r = wm + m * 16 + (l & 15);
                af[m] = *(const short8*)&Asm[r * 128 + ((gg ^ (r & 7)) << 3)];
            }
#pragma unroll
            for (int n = 0; n < 4; ++n) {
                int c = wn + n * 16 + (l & 15);
                bfr[n] = *(const short8*)&Bsm[c * 128 + ((gg ^ (c & 7)) << 3)];
            }
#pragma unroll
            for (int m = 0; m < 4; ++m)
#pragma unroll
                for (int n = 0; n < 4; ++n)
                    acc[m][n] = __builtin_amdgcn_mfma_f32_16x16x32_bf16(
                        af[m], bfr[n], acc[m][n], 0, 0, 0);
        }
    }

    float bcol[4];
#pragma unroll
    for (int n = 0; n < 4; ++n) bcol[n] = bc[wn + n * 16 + (l & 15)];
    float lsum = 0.f;
#pragma unroll
    for (int m = 0; m < 4; ++m) {
        int rbase = wm + m * 16 + ((l >> 4) << 2);   // C/D: row = 4*(l>>4)+reg
#pragma unroll
        for (int n = 0; n < 4; ++n) {
            int col = wn + n * 16 + (l & 15);        // C/D: col = l&15
#pragma unroll
            for (int r = 0; r < 4; ++r) {
                float v = fmaxf(acc[m][n][r] + bcol[n], 0.f);
                out[(row0 + rbase + r) * 128 + col] = v;
                lsum += v * v;
            }
        }
    }
#pragma unroll
    for (int off = 32; off > 0; off >>= 1) lsum += __shfl_down(lsum, off);
    if (l == 0) wred[w] = lsum;
    __syncthreads();
    if (tid == 0)
        partials[blockIdx.x] = wred[0] + wred[1] + wred[2] + wred[3];
}

// ---------------------------------------------------------------------------
// K5 (R4-proven): per-batch frobenius normalize in place; each block
// deterministically reduces its batch's 16 partials. div_no_nan.
// ---------------------------------------------------------------------------
__global__ __launch_bounds__(256) void scale_k(
    float* __restrict__ out, const float* __restrict__ partials)
{
    const int blk = blockIdx.x;
    const int b = blk >> 6;                          // 64 blocks per batch
    float s = 0.f;
#pragma unroll
    for (int i = 0; i < 16; ++i) s += partials[b * 16 + i];
    float norm = sqrtf(s);
    float sc = (norm > 0.f) ? (1.f / norm) : 0.f;
    fvec4* o4 = (fvec4*)out;
    int i0 = blk * 1024 + threadIdx.x;
#pragma unroll
    for (int k = 0; k < 4; ++k) {
        fvec4 v = o4[i0 + k * 256];
        o4[i0 + k * 256] = v * sc;
    }
}

extern "C" void kernel_launch(void* const* d_in, const int* in_sizes, int n_in,
                              void* d_out, int out_size, void* d_ws, size_t ws_size,
                              hipStream_t stream) {
    const float* A  = (const float*)d_in[0];
    const float* X  = (const float*)d_in[1];
    const float* Wa = (const float*)d_in[2];
    const float* ba = (const float*)d_in[3];
    const float* Wc = (const float*)d_in[4];
    const float* bc = (const float*)d_in[5];
    const int*  nsp = (const int*)d_in[6];

    float* out = (float*)d_out;
    char* ws = (char*)d_ws;
    ushort* H        = (ushort*)ws;                              // 8 MB
    ushort* agg      = (ushort*)(ws + (8u << 20));               // 8 MB
    ushort* Wct      = (ushort*)(ws + (16u << 20));              // 64 KB
    float*  partials = (float*) (ws + (16u << 20) + 65536);      // 1 KB

    // K1: H = relu(X @ Wa + ba), inline Wa transpose (no prep dispatch)
    gemm_k1_k<<<256, 256, 0, stream>>>(X, Wa, ba, H);
    // K2: agg = max over first-S neighbors (+ folded Wct prep blocks >= 8192)
    agg_k<<<8192 + 128, 256, 0, stream>>>(A, (const uint*)H, ba, (uint*)agg,
                                          nsp, Wc, Wct);
    // K3: out = relu([X|agg] @ Wc + bc) + partial sumsq
    gemm_k3_k<<<256, 256, 0, stream>>>(X, agg, Wct, bc, out, partials);
    // K5: normalize
    scale_k<<<1024, 256, 0, stream>>>(out, partials);
}